// Round 6
// baseline (366.659 us; speedup 1.0000x reference)
//
#include <hip/hip_runtime.h>

// MEASUREMENT PROBE (intentional 2x work, bit-identical result):
// The kernel never appears in rocprof top-5 (hidden under ~160us harness
// fills), so its true duration is unknown (83us vs 43us both fit dur_us).
// Run the et sweep TWICE -- second pass offset by runtime rep_stride=0 so
// the compiler cannot CSE the loads; nt loads keep both passes pure-HBM.
// Doubled kernel (~2x true time) either surfaces in top-5 (-> exact dur +
// FETCH/BW) or the dur_us delta vs R5 (333.0) gives the 1-pass time.
//
// Math unchanged from R5: per (b,o), out = sgn * max_i(candidate), where
// candidate = et==0 ? -2.0 (never wins: real et==0 value is <= -9 after
// sgn-folding, et!=0 in [-1,1], and >=1 et!=0 exists per row)
//           : sgn * (et==2 ? 1-x : x);  sgn = is_tnorm ? -1 : +1.

constexpr int B = 64;
constexpr int I = 1024;
constexpr int O = 1024;
constexpr int ROWS_PER_WAVE = 4;
constexpr int BLOCKS = (B * O) / (ROWS_PER_WAVE * 4);   // 4096

typedef int   iv4 __attribute__((ext_vector_type(4)));
typedef float fv4 __attribute__((ext_vector_type(4)));

__global__ __launch_bounds__(256) void ffcl_kernel(
    const float* __restrict__ x,       // [B, I]
    const int*   __restrict__ et,      // [B, O, I]
    const int*   __restrict__ op,      // [O]
    float*       __restrict__ out,     // [B, O]
    long rep_stride)                   // 0 at runtime; opaque to compiler
{
    const int t      = threadIdx.x;
    const int wid    = t >> 6;
    const int lane   = t & 63;
    const int wave   = blockIdx.x * 4 + wid;
    const int r_base = wave * ROWS_PER_WAVE;       // 4 consecutive rows, same b
    const int b      = r_base >> 10;
    const int o_base = r_base & (O - 1);

    const iv4* pe = reinterpret_cast<const iv4*>(et + (size_t)r_base * I) + lane;

    // x strip (cols j*256+lane*4) and 1-x, shared by all rows/passes.
    fv4 xv[4], qv[4];
    #pragma unroll
    for (int j = 0; j < 4; ++j) {
        xv[j] = *reinterpret_cast<const fv4*>(x + (size_t)b * I + j * 256 + lane * 4);
        qv[j].x = 1.0f - xv[j].x;  qv[j].y = 1.0f - xv[j].y;
        qv[j].z = 1.0f - xv[j].z;  qv[j].w = 1.0f - xv[j].w;
    }

    float sgn[4];
    #pragma unroll
    for (int rr = 0; rr < 4; ++rr)
        sgn[rr] = (op[o_base + rr] == 0) ? -1.0f : 1.0f;   // min(v) = -max(-v)

    float acc[4];
    #pragma unroll
    for (int rr = 0; rr < 4; ++rr) acc[rr] = -3.0e38f;

    for (int pass = 0; pass < 2; ++pass) {
        const iv4* pp = pe + (size_t)(pass * rep_stride);  // runtime-0 offset

        iv4 e[16];
        #pragma unroll
        for (int rr = 0; rr < 4; ++rr)
            #pragma unroll
            for (int j = 0; j < 4; ++j)
                e[rr * 4 + j] = __builtin_nontemporal_load(&pp[rr * 256 + j * 64]);

        #pragma unroll
        for (int rr = 0; rr < 4; ++rr) {
            const float s = sgn[rr];
            #pragma unroll
            for (int j = 0; j < 4; ++j) {
                const iv4 ev = e[rr * 4 + j];
                float c0, c1, c2, c3;
                c0 = s * ((ev.x == 2) ? qv[j].x : xv[j].x);  c0 = (ev.x == 0) ? -2.0f : c0;
                c1 = s * ((ev.y == 2) ? qv[j].y : xv[j].y);  c1 = (ev.y == 0) ? -2.0f : c1;
                c2 = s * ((ev.z == 2) ? qv[j].z : xv[j].z);  c2 = (ev.z == 0) ? -2.0f : c2;
                c3 = s * ((ev.w == 2) ? qv[j].w : xv[j].w);  c3 = (ev.w == 0) ? -2.0f : c3;
                acc[rr] = fmaxf(fmaxf(acc[rr], c0), c1);
                acc[rr] = fmaxf(fmaxf(acc[rr], c2), c3);
            }
        }
    }

    float keep = 0.0f;
    #pragma unroll
    for (int rr = 0; rr < 4; ++rr) {
        float a = acc[rr];
        #pragma unroll
        for (int s = 32; s > 0; s >>= 1)
            a = fmaxf(a, __shfl_xor(a, s, 64));
        if (lane == rr) keep = sgn[rr] * a;
    }
    if (lane < ROWS_PER_WAVE)
        out[r_base + lane] = keep;
}

extern "C" void kernel_launch(void* const* d_in, const int* in_sizes, int n_in,
                              void* d_out, int out_size, void* d_ws, size_t ws_size,
                              hipStream_t stream) {
    const float* x   = (const float*)d_in[0];
    const int*   et  = (const int*)d_in[1];
    const int*   op  = (const int*)d_in[2];
    float*       out = (float*)d_out;

    ffcl_kernel<<<BLOCKS, 256, 0, stream>>>(x, et, op, out, 0L);
}